// Round 1
// baseline (480.335 us; speedup 1.0000x reference)
//
#include <hip/hip_runtime.h>
#include <hip/hip_bf16.h>

// CausalLinearAttention — bf16-MFMA, 3-pass segment-parallel scan.
// N=4, L=8192, H=16, E=D=64. This revision:
//  * pass3: 4 LDS arrays (Stb folded into Kb after m1) -> 38.1KB -> 4 blocks/CU,
//    G=16 grid = 1024 = 4*256 single dispatch round (was 3/CU + tail).
//  * all wave0-serial 64-iter reductions replaced by register/shuffle
//    reductions (dden, rs, z) and 256-thread partials (ksum/ksr).
//  * pass1 + pass3-V transposed staging: 4x4 register-block transpose,
//    packed 8B LDS stores (was 16 scalar 2B @ 4-way conflict per array).
//  * pass2 widened to NHh*17 blocks.

#define Nn   4
#define Ll   8192
#define Hh   16
#define NHh  64
#define CCH  64          // chunk size (positions)
#define LDB  72          // bf16 LDS row stride: 144 B, 16B-multiple
#define SLOT 4160        // per-(nh,seg) ws slot: 4096 state + 64 ksum floats
#define EPSF 1e-6f

typedef __attribute__((ext_vector_type(8))) short short8;   // 8 bf16 = 4 VGPRs
typedef __attribute__((ext_vector_type(4))) float floatx4;  // MFMA accumulator

__device__ __forceinline__ float elu1(float x) {
  return x > 0.f ? x + 1.f : __expf(x);
}

__device__ __forceinline__ float4 elu4(float4 v) {
  v.x = elu1(v.x); v.y = elu1(v.y); v.z = elu1(v.z); v.w = elu1(v.w);
  return v;
}

__device__ __forceinline__ floatx4 mfma16(short8 a, short8 b, floatx4 c) {
  return __builtin_amdgcn_mfma_f32_16x16x32_bf16(a, b, c, 0, 0, 0);
}

// load an A/B fragment: row-major [row][k], 8 consecutive bf16 at
// k = kh*32 + quad*8
__device__ __forceinline__ short8 frag_ld(const __hip_bfloat16* base, int row,
                                          int kh, int quad) {
  return *(const short8*)(base + row * LDB + kh * 32 + quad * 8);
}

// pack 4 floats -> 4 bf16, single 8-byte LDS write (dst must be 8B-aligned)
__device__ __forceinline__ void st4bf(__hip_bfloat16* dst, float a, float b,
                                      float c, float d) {
  union { __hip_bfloat16 h[4]; uint2 u; } pk;
  pk.h[0] = __float2bfloat16(a); pk.h[1] = __float2bfloat16(b);
  pk.h[2] = __float2bfloat16(c); pk.h[3] = __float2bfloat16(d);
  *(uint2*)dst = pk.u;
}

__device__ __forceinline__ float bf2f(short s) {
  union { unsigned u; float f; } cv;
  cv.u = ((unsigned)(unsigned short)s) << 16;
  return cv.f;
}

__device__ __forceinline__ float sum8bf(short8 v) {
  float s = 0.f;
#pragma unroll
  for (int i = 0; i < 8; ++i) s += bf2f(v[i]);
  return s;
}

// ---------------------------------------------------------------- pass 1
// per-(nh,seg): partial S^T = V^T K (64x64) and ksum (64), written to ws.
__global__ __launch_bounds__(256, 4) void la_pass1(
    const float* __restrict__ Kg, const float* __restrict__ Vg,
    float* __restrict__ ws, int G, int Lseg) {
  const int bid = blockIdx.x;
  const int nh = bid / G, g = bid % G;
  const int n = nh / Hh, h = nh % Hh;
  const int t = threadIdx.x;
  const int wave = t >> 6, lane = t & 63, m = lane & 15, quad = lane >> 4;
  // 4x4-block transposed staging coords: rows j (source), cols e (dest rows)
  const int jr0 = m * 4;
  const int er0 = wave * 16 + quad * 4;

  __shared__ __hip_bfloat16 Ktb[64 * LDB];  // K^T [e][j]
  __shared__ __hip_bfloat16 Vtb[64 * LDB];  // V^T [d][j]
  __shared__ float kpart[4][64];

  floatx4 Sacc[4];  // S^T tiles: rows d = 16*wave + quad*4 + r, cols e = 16*b + m
  const floatx4 z4 = {0.f, 0.f, 0.f, 0.f};
#pragma unroll
  for (int b = 0; b < 4; ++b) Sacc[b] = z4;
  float ksr = 0.f;

  const int nchunk = Lseg / CCH;
  for (int c = 0; c < nchunk; ++c) {
    const size_t gb =
        ((size_t)((n * Ll + g * Lseg + c * CCH + jr0) * Hh + h)) * 64 + er0;
    float4 k0 = elu4(*(const float4*)(Kg + gb));
    float4 k1 = elu4(*(const float4*)(Kg + gb + 1024));
    float4 k2 = elu4(*(const float4*)(Kg + gb + 2048));
    float4 k3 = elu4(*(const float4*)(Kg + gb + 3072));
    float4 v0 = *(const float4*)(Vg + gb);
    float4 v1 = *(const float4*)(Vg + gb + 1024);
    float4 v2 = *(const float4*)(Vg + gb + 2048);
    float4 v3 = *(const float4*)(Vg + gb + 3072);
    // register 4x4 transpose -> packed 8B stores
    st4bf(&Ktb[(er0 + 0) * LDB + jr0], k0.x, k1.x, k2.x, k3.x);
    st4bf(&Ktb[(er0 + 1) * LDB + jr0], k0.y, k1.y, k2.y, k3.y);
    st4bf(&Ktb[(er0 + 2) * LDB + jr0], k0.z, k1.z, k2.z, k3.z);
    st4bf(&Ktb[(er0 + 3) * LDB + jr0], k0.w, k1.w, k2.w, k3.w);
    st4bf(&Vtb[(er0 + 0) * LDB + jr0], v0.x, v1.x, v2.x, v3.x);
    st4bf(&Vtb[(er0 + 1) * LDB + jr0], v0.y, v1.y, v2.y, v3.y);
    st4bf(&Vtb[(er0 + 2) * LDB + jr0], v0.z, v1.z, v2.z, v3.z);
    st4bf(&Vtb[(er0 + 3) * LDB + jr0], v0.w, v1.w, v2.w, v3.w);
    __syncthreads();  // B1: tiles staged

    const short8 a0 = frag_ld(Vtb, 16 * wave + m, 0, quad);
    const short8 a1 = frag_ld(Vtb, 16 * wave + m, 1, quad);
    __builtin_amdgcn_s_setprio(1);
#pragma unroll
    for (int b = 0; b < 4; ++b) {
      Sacc[b] = mfma16(a0, frag_ld(Ktb, 16 * b + m, 0, quad), Sacc[b]);
      Sacc[b] = mfma16(a1, frag_ld(Ktb, 16 * b + m, 1, quad), Sacc[b]);
    }
    __builtin_amdgcn_s_setprio(0);
    {  // ksum partials: thread sums 16 j's of row e = lane
      const short8 x0 = *(const short8*)(&Ktb[lane * LDB + wave * 16]);
      const short8 x1 = *(const short8*)(&Ktb[lane * LDB + wave * 16 + 8]);
      kpart[wave][lane] = sum8bf(x0) + sum8bf(x1);
    }
    __syncthreads();  // B2: reads of this chunk done
    if (t < 64) ksr += kpart[0][t] + kpart[1][t] + kpart[2][t] + kpart[3][t];
  }
  const size_t slot = (size_t)bid * SLOT;
#pragma unroll
  for (int b = 0; b < 4; ++b)
#pragma unroll
    for (int r = 0; r < 4; ++r) {
      const int d = 16 * wave + quad * 4 + r, e = 16 * b + m;
      ws[slot + d * 64 + e] = Sacc[b][r];
    }
  if (t < 64) ws[slot + 4096 + t] = ksr;
}

// ---------------------------------------------------------------- pass 2
// exclusive scan over segments; one element per thread, NHh*17 blocks.
__global__ __launch_bounds__(256) void la_pass2(float* __restrict__ ws, int G) {
  const int nh = blockIdx.x / 17, part = blockIdx.x % 17;
  const int idx = part * 256 + threadIdx.x;
  if (idx >= SLOT) return;
  float run = 0.f;
  for (int g = 0; g < G; ++g) {
    const size_t base = (size_t)(nh * G + g) * SLOT;
    const float cur = ws[base + idx];
    ws[base + idx] = run;
    run += cur;
  }
}

// ---------------------------------------------------------------- pass 3
__global__ __launch_bounds__(256, 4) void la_pass3(
    const float* __restrict__ Qg, const float* __restrict__ Kg,
    const float* __restrict__ Vg, const float* __restrict__ ws,
    float* __restrict__ out, int G, int Lseg, int has_prefix) {
  const int bid = blockIdx.x;
  const int nh = bid / G, g = bid % G;
  const int n = nh / Hh, h = nh % Hh;
  const int t = threadIdx.x;
  const int wave = t >> 6, lane = t & 63, m = lane & 15, quad = lane >> 4;
  const int row = t >> 2, q4 = t & 3;      // row-major staging coords
  const int jr0 = m * 4;                   // V 4x4-block transposed staging
  const int er0 = wave * 16 + quad * 4;

  __shared__ __hip_bfloat16 QPb[64 * LDB];  // Q [i][e], then masked P [i][j]
  __shared__ __hip_bfloat16 Kb [64 * LDB];  // K [j][e], then S^T snapshot [d][e]
  __shared__ __hip_bfloat16 Ktb[64 * LDB];  // K^T [e][j]
  __shared__ __hip_bfloat16 Vtb[64 * LDB];  // V^T [d][j]
  __shared__ float ksum[64];
  __shared__ float kpart[4][64];

  const size_t slot = (size_t)bid * SLOT;
  floatx4 Sacc[4];  // persistent S^T: rows d = 16*wave+quad*4+r, cols e = 16*b+m
  const floatx4 z4 = {0.f, 0.f, 0.f, 0.f};
#pragma unroll
  for (int b = 0; b < 4; ++b) {
    Sacc[b] = z4;
    if (has_prefix) {
#pragma unroll
      for (int r = 0; r < 4; ++r)
        Sacc[b][r] = ws[slot + (16 * wave + quad * 4 + r) * 64 + 16 * b + m];
    }
  }
  if (t < 64) ksum[t] = has_prefix ? ws[slot + 4096 + t] : 0.f;

  const int nchunk = Lseg / CCH;
  for (int c = 0; c < nchunk; ++c) {
    const int lbase = g * Lseg + c * CCH;
    // ---- phase A: stage Q,K (row-major + scalar-transposed K) and V (4x4)
    const size_t gbr = ((size_t)((n * Ll + lbase + row) * Hh + h)) * 64;
#pragma unroll
    for (int u = 0; u < 4; ++u) {
      const int col = u * 16 + q4 * 4;
      float4 qv = elu4(*(const float4*)(Qg + gbr + col));
      float4 kv = elu4(*(const float4*)(Kg + gbr + col));
      st4bf(&QPb[row * LDB + col], qv.x, qv.y, qv.z, qv.w);
      st4bf(&Kb [row * LDB + col], kv.x, kv.y, kv.z, kv.w);
      Ktb[(col + 0) * LDB + row] = __float2bfloat16(kv.x);
      Ktb[(col + 1) * LDB + row] = __float2bfloat16(kv.y);
      Ktb[(col + 2) * LDB + row] = __float2bfloat16(kv.z);
      Ktb[(col + 3) * LDB + row] = __float2bfloat16(kv.w);
    }
    {
      const size_t gbv =
          ((size_t)((n * Ll + lbase + jr0) * Hh + h)) * 64 + er0;
      float4 v0 = *(const float4*)(Vg + gbv);
      float4 v1 = *(const float4*)(Vg + gbv + 1024);
      float4 v2 = *(const float4*)(Vg + gbv + 2048);
      float4 v3 = *(const float4*)(Vg + gbv + 3072);
      st4bf(&Vtb[(er0 + 0) * LDB + jr0], v0.x, v1.x, v2.x, v3.x);
      st4bf(&Vtb[(er0 + 1) * LDB + jr0], v0.y, v1.y, v2.y, v3.y);
      st4bf(&Vtb[(er0 + 2) * LDB + jr0], v0.z, v1.z, v2.z, v3.z);
      st4bf(&Vtb[(er0 + 3) * LDB + jr0], v0.w, v1.w, v2.w, v3.w);
    }
    __syncthreads();  // B1: tiles staged

    // ---- phase B: m1 (sc = Q K^T) + denominator in registers
    const short8 qa0 = frag_ld(QPb, 16 * wave + m, 0, quad);
    const short8 qa1 = frag_ld(QPb, 16 * wave + m, 1, quad);
    floatx4 sc[4];
    __builtin_amdgcn_s_setprio(1);
#pragma unroll
    for (int b = 0; b < 4; ++b) {
      sc[b] = mfma16(qa0, frag_ld(Kb, 16 * b + m, 0, quad), z4);
      sc[b] = mfma16(qa1, frag_ld(Kb, 16 * b + m, 1, quad), sc[b]);
    }
    __builtin_amdgcn_s_setprio(0);
    // dden for row i' = 16*wave + m from register fragments:
    // qa0 covers e = quad*8..+7, qa1 covers e = 32+quad*8..+7
    float dpart = 0.f;
    {
      const float* ks0 = &ksum[quad * 8];        // broadcast reads
      const float* ks1 = &ksum[32 + quad * 8];
#pragma unroll
      for (int u = 0; u < 8; ++u) dpart += bf2f(qa0[u]) * ks0[u];
#pragma unroll
      for (int u = 0; u < 8; ++u) dpart += bf2f(qa1[u]) * ks1[u];
    }
    dpart += __shfl_xor(dpart, 16);
    dpart += __shfl_xor(dpart, 32);  // all lanes: full dden[16*wave + m]
    // rs[r] = sum_j masked sc; z[r] in registers (no zS LDS)
    float z[4];
#pragma unroll
    for (int r = 0; r < 4; ++r) {
      const int i = 16 * wave + quad * 4 + r;
      float rs = 0.f;
#pragma unroll
      for (int b = 0; b < 4; ++b) {
        const int j = 16 * b + m;
        rs += (j <= i) ? sc[b][r] : 0.f;
      }
      rs += __shfl_xor(rs, 1);
      rs += __shfl_xor(rs, 2);
      rs += __shfl_xor(rs, 4);
      rs += __shfl_xor(rs, 8);
      const float den = __shfl(dpart, quad * 4 + r);  // lane m' = quad*4+r
      z[r] = 1.f / (den + rs + EPSF);
    }
    __syncthreads();  // B2: Q/Kb reads done; QPb->P, Kb->snapshot next

    // ---- phase C: write masked P into QPb; snapshot S^T into Kb
#pragma unroll
    for (int b = 0; b < 4; ++b)
#pragma unroll
      for (int r = 0; r < 4; ++r) {
        const int i = 16 * wave + quad * 4 + r, j = 16 * b + m;
        QPb[i * LDB + j] = __float2bfloat16(j <= i ? sc[b][r] : 0.f);
        Kb[i * LDB + j] = __float2bfloat16(Sacc[b][r]);  // rows d, cols e
      }
    __syncthreads();  // B3: P + snapshot visible

    // ---- phase D: m2 (Q S_prev) + m3 (P V) + m4 (S += V^T K)
    const short8 pa0 = frag_ld(QPb, 16 * wave + m, 0, quad);
    const short8 pa1 = frag_ld(QPb, 16 * wave + m, 1, quad);
    const short8 va0 = frag_ld(Vtb, 16 * wave + m, 0, quad);
    const short8 va1 = frag_ld(Vtb, 16 * wave + m, 1, quad);
    floatx4 O[4];
    __builtin_amdgcn_s_setprio(1);
#pragma unroll
    for (int b = 0; b < 4; ++b) {
      O[b] = mfma16(qa0, frag_ld(Kb, 16 * b + m, 0, quad), z4);
      O[b] = mfma16(qa1, frag_ld(Kb, 16 * b + m, 1, quad), O[b]);
      O[b] = mfma16(pa0, frag_ld(Vtb, 16 * b + m, 0, quad), O[b]);
      O[b] = mfma16(pa1, frag_ld(Vtb, 16 * b + m, 1, quad), O[b]);
      Sacc[b] = mfma16(va0, frag_ld(Ktb, 16 * b + m, 0, quad), Sacc[b]);
      Sacc[b] = mfma16(va1, frag_ld(Ktb, 16 * b + m, 1, quad), Sacc[b]);
    }
    __builtin_amdgcn_s_setprio(0);
    {  // ksum partials for next chunk
      const short8 x0 = *(const short8*)(&Ktb[lane * LDB + wave * 16]);
      const short8 x1 = *(const short8*)(&Ktb[lane * LDB + wave * 16 + 8]);
      kpart[wave][lane] = sum8bf(x0) + sum8bf(x1);
    }
    const size_t ob = ((size_t)((n * Ll + lbase) * Hh + h)) * 64;
#pragma unroll
    for (int r = 0; r < 4; ++r) {
      const int i = 16 * wave + quad * 4 + r;
#pragma unroll
      for (int b = 0; b < 4; ++b)
        out[ob + (size_t)i * (Hh * 64) + 16 * b + m] = O[b][r] * z[r];
    }
    __syncthreads();  // B4: all LDS reads of this chunk done
    if (t < 64)
      ksum[t] += kpart[0][t] + kpart[1][t] + kpart[2][t] + kpart[3][t];
  }
}

// ---------------------------------------------------------------- launch
extern "C" void kernel_launch(void* const* d_in, const int* in_sizes, int n_in,
                              void* d_out, int out_size, void* d_ws, size_t ws_size,
                              hipStream_t stream) {
  (void)in_sizes; (void)n_in; (void)out_size;
  const float* Qg = (const float*)d_in[0];
  const float* Kg = (const float*)d_in[1];
  const float* Vg = (const float*)d_in[2];
  float* out = (float*)d_out;
  float* ws = (float*)d_ws;

  const size_t per_seg = (size_t)NHh * SLOT * sizeof(float);
  int G = 1;
  if (ws_size >= 16 * per_seg) G = 16;
  else if (ws_size >= 8 * per_seg) G = 8;
  else if (ws_size >= 4 * per_seg) G = 4;
  else if (ws_size >= 2 * per_seg) G = 2;
  const int Lseg = Ll / G;

  if (G > 1) {
    la_pass1<<<NHh * G, 256, 0, stream>>>(Kg, Vg, ws, G, Lseg);
    la_pass2<<<NHh * 17, 256, 0, stream>>>(ws, G);
  }
  la_pass3<<<NHh * G, 256, 0, stream>>>(Qg, Kg, Vg, ws, out, G, Lseg, G > 1 ? 1 : 0);
}